// Round 12
// baseline (579.509 us; speedup 1.0000x reference)
//
#include <hip/hip_runtime.h>
#include <hip/hip_bf16.h>

// Problem constants
constexpr int Nn  = 20000;
constexpr int Ee  = 320000;
constexpr int Hh  = 6;
constexpr int HC  = 384;   // Hh*64
constexpr int Gg  = 64;
constexpr int NF  = 6;
constexpr int EP  = Ee + Nn;  // edges incl self-loops
constexpr int HW  = HC / 2;   // 192 packed u32 words per node row

typedef __attribute__((ext_vector_type(8))) short short8;
typedef __attribute__((ext_vector_type(4))) float f32x4;

// ---------------- workspace layout (bytes) ----------------
constexpr size_t ALN(size_t x) { return (x + 255) & ~(size_t)255; }
constexpr size_t OFF_H1BF = 0;                                   // N*192 u32 (h1, reused as h2)
constexpr size_t OFF_X2BF = ALN(OFF_H1BF + (size_t)Nn*HW*4);     // N*192 u32
constexpr size_t OFF_ATT  = ALN(OFF_X2BF + (size_t)Nn*HW*4);     // EP*6 f32 (alpha scratch -> e values)
constexpr size_t OFF_DEN  = ALN(OFF_ATT  + (size_t)EP*Hh*4);     // N*6 f32 (softmax denominators)
constexpr size_t OFF_AS1  = ALN(OFF_DEN  + (size_t)Nn*Hh*4);
constexpr size_t OFF_AD1  = ALN(OFF_AS1  + (size_t)Nn*Hh*4);
constexpr size_t OFF_AS2  = ALN(OFF_AD1  + (size_t)Nn*Hh*4);
constexpr size_t OFF_AD2  = ALN(OFF_AS2  + (size_t)Nn*Hh*4);
constexpr size_t OFF_OFFS = ALN(OFF_AD2  + (size_t)Nn*Hh*4);     // (N+1) int
constexpr size_t OFF_ESRC = ALN(OFF_OFFS + (size_t)(Nn+1)*4);
constexpr size_t OFF_EEA  = ALN(OFF_ESRC + (size_t)EP*4);
constexpr size_t OFF_W2BF = ALN(OFF_EEA  + (size_t)EP*4);        // 384*384 bf16
// ---- zeroed block (single memset) ----
constexpr size_t OFF_ZERO = ALN(OFF_W2BF + (size_t)HC*HC*2);
constexpr size_t OFF_CNT  = OFF_ZERO;                            // N int
constexpr size_t OFF_CNT2 = OFF_CNT  + (size_t)Nn*4;             // N int
constexpr size_t OFF_CNTG = OFF_CNT2 + (size_t)Nn*4;             // G int
constexpr size_t OFF_POOL = OFF_CNTG + (size_t)Gg*4;             // G*HC f32
constexpr size_t OFF_SCAL = OFF_POOL + (size_t)Gg*HC*4;          // 64 f32
constexpr size_t ZERO_BYTES = OFF_SCAL + 64*4 - OFF_ZERO;

// ---------------- helpers ----------------
__device__ __forceinline__ float wave_red64(float v) {
    #pragma unroll
    for (int o = 32; o; o >>= 1) v += __shfl_down(v, o);
    return v;
}
__device__ __forceinline__ unsigned short f2bf(float f) {
    union { float f; unsigned u; } v; v.f = f;
    return (unsigned short)((v.u + 0x7fffu + ((v.u >> 16) & 1u)) >> 16);
}
__device__ __forceinline__ unsigned pack2(float a, float b) {
    return (unsigned)f2bf(a) | ((unsigned)f2bf(b) << 16);
}
__device__ __forceinline__ float blo(unsigned w) { union { unsigned u; float f; } v; v.u = w << 16; return v.f; }
__device__ __forceinline__ float bhi(unsigned w) { union { unsigned u; float f; } v; v.u = w & 0xffff0000u; return v.f; }

// -------- fused: mean of edge_attr + w2->bf16 --------
__global__ void k_prep(const float* __restrict__ ea, float* __restrict__ scal,
                       const float* __restrict__ w2, unsigned short* __restrict__ w2bf) {
    int i = blockIdx.x * blockDim.x + threadIdx.x;
    int stride = gridDim.x * blockDim.x;
    float v = 0.f;
    for (int j = i; j < Ee; j += stride) v += ea[j];
    v = wave_red64(v);
    if ((threadIdx.x & 63) == 0) atomicAdd(&scal[0], v);
    for (int j = i; j < HC * HC; j += stride) w2bf[j] = f2bf(w2[j]);
}

// -------- we_dot[h] for both layers --------
__global__ void k_wedot(const float* __restrict__ we1, const float* __restrict__ atte1,
                        const float* __restrict__ we2, const float* __restrict__ atte2,
                        float* __restrict__ scal) {
    int t = threadIdx.x;  // 384
    float p1 = we1[t] * atte1[t];
    float p2 = we2[t] * atte2[t];
    p1 = wave_red64(p1);
    p2 = wave_red64(p2);
    if ((t & 63) == 0) { int h = t >> 6; scal[1 + h] = p1; scal[7 + h] = p2; }
}

// -------- h1 = x @ W1^T (bf16 packed), attention dots --------
__global__ __launch_bounds__(HW) void k_h1(const float* __restrict__ x, const float* __restrict__ w1,
                                           const float* __restrict__ asrc, const float* __restrict__ adst,
                                           unsigned* __restrict__ h1bf, float* __restrict__ as_, float* __restrict__ ad_) {
    int n = blockIdx.x, t = threadIdx.x;
    int c0 = 2 * t, c1 = c0 + 1;
    float xv[NF];
    #pragma unroll
    for (int k = 0; k < NF; k++) xv[k] = x[n * NF + k];
    float a0 = 0.f, a1 = 0.f;
    #pragma unroll
    for (int k = 0; k < NF; k++) { a0 += xv[k] * w1[c0 * NF + k]; a1 += xv[k] * w1[c1 * NF + k]; }
    h1bf[(size_t)n * HW + t] = pack2(a0, a1);
    float s = a0 * asrc[c0] + a1 * asrc[c1];
    float d = a0 * adst[c0] + a1 * adst[c1];
    #pragma unroll
    for (int o = 16; o; o >>= 1) { s += __shfl_xor(s, o); d += __shfl_xor(d, o); }
    if ((t & 31) == 0) { int h = t >> 5; as_[n * Hh + h] = s; ad_[n * Hh + h] = d; }
}

// -------- CSR build: count incoming edges + per-graph node counts --------
__global__ void k_count(const int* __restrict__ dst, int* __restrict__ cnt,
                        const int* __restrict__ batch, int* __restrict__ cntg) {
    int i = blockIdx.x * blockDim.x + threadIdx.x;
    if (i < EP) {
        int d = (i < Ee) ? dst[i] : (i - Ee);
        atomicAdd(&cnt[d], 1);
    }
    if (i < Nn) atomicAdd(&cntg[batch[i]], 1);
}

__global__ __launch_bounds__(1024) void k_scan(const int* __restrict__ cnt, int* __restrict__ offs) {
    __shared__ int wsum[16];
    __shared__ int carry_s;
    int t = threadIdx.x, lane = t & 63, wid = t >> 6;
    if (t == 0) carry_s = 0;
    __syncthreads();
    for (int base = 0; base < Nn; base += 1024) {
        int idx = base + t;
        int v = (idx < Nn) ? cnt[idx] : 0;
        int x = v;
        #pragma unroll
        for (int o = 1; o < 64; o <<= 1) { int y = __shfl_up(x, o); if (lane >= o) x += y; }
        if (lane == 63) wsum[wid] = x;
        __syncthreads();
        int wbase = 0;
        for (int i = 0; i < wid; i++) wbase += wsum[i];
        int excl = carry_s + wbase + x - v;
        if (idx < Nn) offs[idx] = excl;
        __syncthreads();
        if (t == 1023) carry_s = excl + v;
        __syncthreads();
    }
    if (t == 0) offs[Nn] = carry_s;
}

__global__ void k_scatter(const int* __restrict__ src, const int* __restrict__ dst,
                          const float* __restrict__ ea, const int* __restrict__ offs,
                          int* __restrict__ cnt2, int* __restrict__ esrc, float* __restrict__ eea,
                          const float* __restrict__ scal) {
    int i = blockIdx.x * blockDim.x + threadIdx.x;
    if (i >= EP) return;
    int d, s; float a;
    if (i < Ee) { d = dst[i]; s = src[i]; a = ea[i]; }
    else        { d = i - Ee; s = d; a = scal[0] * (1.0f / Ee); }
    int p = offs[d] + atomicAdd(&cnt2[d], 1);
    esrc[p] = s;
    eea[p]  = a;
}

// -------- per-(node,head) softmax: att[] gets e=exp(al-m); den[] gets sum --------
template <int LAYER>
__global__ void k_att(const float* __restrict__ as_, const float* __restrict__ ad_,
                      const int* __restrict__ offs, const int* __restrict__ esrc,
                      const float* __restrict__ eea, const float* __restrict__ scal,
                      float* __restrict__ att, float* __restrict__ den_out) {
    int idx = blockIdx.x * blockDim.x + threadIdx.x;
    if (idx >= Nn * Hh) return;
    int n = idx / Hh, h = idx - n * Hh;
    int s0 = offs[n], s1 = offs[n + 1];
    float adn = ad_[idx];
    float wdh = scal[(LAYER == 1 ? 1 : 7) + h];
    float m = -3.4e38f;
    // pass 1: gather (4-deep MLP), compute alpha, store raw, track max
    int j = s0;
    for (; j + 3 < s1; j += 4) {
        int sa = esrc[j], sb = esrc[j+1], sc = esrc[j+2], sd = esrc[j+3];
        float ea0 = eea[j], ea1 = eea[j+1], ea2 = eea[j+2], ea3 = eea[j+3];
        float va = as_[sa * Hh + h];
        float vb = as_[sb * Hh + h];
        float vc = as_[sc * Hh + h];
        float vd = as_[sd * Hh + h];
        float A = va + adn + ea0 * wdh; A = (A > 0.f) ? A : 0.2f * A;
        float B = vb + adn + ea1 * wdh; B = (B > 0.f) ? B : 0.2f * B;
        float C = vc + adn + ea2 * wdh; C = (C > 0.f) ? C : 0.2f * C;
        float D = vd + adn + ea3 * wdh; D = (D > 0.f) ? D : 0.2f * D;
        att[j * Hh + h] = A; att[(j+1) * Hh + h] = B;
        att[(j+2) * Hh + h] = C; att[(j+3) * Hh + h] = D;
        m = fmaxf(m, fmaxf(fmaxf(A, B), fmaxf(C, D)));
    }
    for (; j < s1; ++j) {
        int s = esrc[j];
        float al = as_[s * Hh + h] + adn + eea[j] * wdh;
        al = (al > 0.f) ? al : 0.2f * al;
        att[j * Hh + h] = al;
        m = fmaxf(m, al);
    }
    // pass 2: e = exp(al - m) over our own sequential buffer; accumulate den
    float den = 0.f;
    for (j = s0; j < s1; ++j) {
        float e = __expf(att[j * Hh + h] - m);
        att[j * Hh + h] = e;
        den += e;
    }
    den_out[idx] = den;
}

// -------- aggregation: gather-weighted sum (bf16 rows, 8B/lane, 4-edge MLP) --------
// 192 threads = 2 nodes x 96 threads; each thread owns 4 channels.
template <int LAYER>
__global__ __launch_bounds__(192) void k_agg(const uint2* __restrict__ hbf2, const float* __restrict__ att,
                                             const float* __restrict__ den, const int* __restrict__ offs,
                                             const int* __restrict__ esrc, const float* __restrict__ bias,
                                             const int* __restrict__ batch,
                                             uint2* __restrict__ xout, float* __restrict__ pool) {
    int t = threadIdx.x;
    int sub = t / 96, tt = t - sub * 96;
    int n = blockIdx.x * 2 + sub;
    int h = tt >> 4;             // 16 threads (64 ch) per head
    int s0 = offs[n], s1 = offs[n + 1];
    float x0a=0.f,x1a=0.f,x2a=0.f,x3a=0.f;
    float x0b=0.f,x1b=0.f,x2b=0.f,x3b=0.f;
    float x0c=0.f,x1c=0.f,x2c=0.f,x3c=0.f;
    float x0d=0.f,x1d=0.f,x2d=0.f,x3d=0.f;
    int j = s0;
    for (; j + 3 < s1; j += 4) {
        int sa = esrc[j], sb = esrc[j+1], sc = esrc[j+2], sd = esrc[j+3];
        uint2 wa = hbf2[(size_t)sa * 96 + tt];
        uint2 wb = hbf2[(size_t)sb * 96 + tt];
        uint2 wc = hbf2[(size_t)sc * 96 + tt];
        uint2 wd = hbf2[(size_t)sd * 96 + tt];
        float fa = att[j * Hh + h], fb = att[(j+1) * Hh + h];
        float fc = att[(j+2) * Hh + h], fd = att[(j+3) * Hh + h];
        x0a += fa * blo(wa.x); x1a += fa * bhi(wa.x); x2a += fa * blo(wa.y); x3a += fa * bhi(wa.y);
        x0b += fb * blo(wb.x); x1b += fb * bhi(wb.x); x2b += fb * blo(wb.y); x3b += fb * bhi(wb.y);
        x0c += fc * blo(wc.x); x1c += fc * bhi(wc.x); x2c += fc * blo(wc.y); x3c += fc * bhi(wc.y);
        x0d += fd * blo(wd.x); x1d += fd * bhi(wd.x); x2d += fd * blo(wd.y); x3d += fd * bhi(wd.y);
    }
    for (; j < s1; ++j) {
        int s = esrc[j];
        uint2 w = hbf2[(size_t)s * 96 + tt];
        float f = att[j * Hh + h];
        x0a += f * blo(w.x); x1a += f * bhi(w.x); x2a += f * blo(w.y); x3a += f * bhi(w.y);
    }
    float rden = 1.f / den[n * Hh + h];
    int c0 = 4 * tt;
    float o0 = (x0a + x0b + x0c + x0d) * rden + bias[c0];
    float o1 = (x1a + x1b + x1c + x1d) * rden + bias[c0 + 1];
    float o2 = (x2a + x2b + x2c + x2d) * rden + bias[c0 + 2];
    float o3 = (x3a + x3b + x3c + x3d) * rden + bias[c0 + 3];
    o0 = (o0 > 0.f) ? o0 : (__expf(o0) - 1.f);
    o1 = (o1 > 0.f) ? o1 : (__expf(o1) - 1.f);
    o2 = (o2 > 0.f) ? o2 : (__expf(o2) - 1.f);
    o3 = (o3 > 0.f) ? o3 : (__expf(o3) - 1.f);
    if (LAYER == 1) {
        xout[(size_t)n * 96 + tt] = make_uint2(pack2(o0, o1), pack2(o2, o3));
    } else {
        float* pp = pool + batch[n] * HC + c0;
        atomicAdd(pp,     o0);
        atomicAdd(pp + 1, o1);
        atomicAdd(pp + 2, o2);
        atomicAdd(pp + 3, o3);
    }
}

// -------- MFMA GEMM: h2 = x2 @ w2^T, bf16 in, bf16 out --------
__global__ __launch_bounds__(256) void k_gemm(const unsigned short* __restrict__ x2bf,
                                              const unsigned short* __restrict__ w2bf,
                                              unsigned short* __restrict__ h2bf) {
    int t = threadIdx.x, l = t & 63, w = t >> 6;
    int m0 = blockIdx.x * 32;
    int n0 = w * 96;
    int lr = l & 15, lk = l >> 4;
    f32x4 acc[2][6];
    #pragma unroll
    for (int mi = 0; mi < 2; mi++)
        #pragma unroll
        for (int f = 0; f < 6; f++) acc[mi][f] = (f32x4){0.f, 0.f, 0.f, 0.f};
    int mrow0 = m0 + lr, mrow1 = m0 + 16 + lr;
    int r0 = mrow0 < Nn ? mrow0 : Nn - 1;
    int r1 = mrow1 < Nn ? mrow1 : Nn - 1;
    for (int ks = 0; ks < HC / 32; ks++) {
        int koff = ks * 32 + lk * 8;
        short8 a0 = *(const short8*)(x2bf + (size_t)r0 * HC + koff);
        short8 a1 = *(const short8*)(x2bf + (size_t)r1 * HC + koff);
        #pragma unroll
        for (int f = 0; f < 6; f++) {
            short8 b = *(const short8*)(w2bf + (size_t)(n0 + f * 16 + lr) * HC + koff);
            acc[0][f] = __builtin_amdgcn_mfma_f32_16x16x32_bf16(a0, b, acc[0][f], 0, 0, 0);
            acc[1][f] = __builtin_amdgcn_mfma_f32_16x16x32_bf16(a1, b, acc[1][f], 0, 0, 0);
        }
    }
    #pragma unroll
    for (int mi = 0; mi < 2; mi++) {
        int rowb = m0 + mi * 16 + lk * 4;
        #pragma unroll
        for (int r = 0; r < 4; r++) {
            int row = rowb + r;
            if (row < Nn) {
                unsigned short* dp = h2bf + (size_t)row * HC + n0 + lr;
                #pragma unroll
                for (int f = 0; f < 6; f++) dp[f * 16] = f2bf(acc[mi][f][r]);
            }
        }
    }
}

// -------- attention dots for layer 2 (bf16 h2) --------
__global__ __launch_bounds__(HW) void k_attn2(const unsigned* __restrict__ h2bf, const float* __restrict__ asrc,
                                              const float* __restrict__ adst,
                                              float* __restrict__ as_, float* __restrict__ ad_) {
    int n = blockIdx.x, t = threadIdx.x;
    unsigned w = h2bf[(size_t)n * HW + t];
    float v0 = blo(w), v1 = bhi(w);
    float s = v0 * asrc[2 * t] + v1 * asrc[2 * t + 1];
    float d = v0 * adst[2 * t] + v1 * adst[2 * t + 1];
    #pragma unroll
    for (int o = 16; o; o >>= 1) { s += __shfl_xor(s, o); d += __shfl_xor(d, o); }
    if ((t & 31) == 0) { int h = t >> 5; as_[n * Hh + h] = s; ad_[n * Hh + h] = d; }
}

// -------- final: mean pool -> linear -> sigmoid --------
__global__ __launch_bounds__(HC) void k_final(const float* __restrict__ pool, const int* __restrict__ cntg,
                                              const float* __restrict__ wlin, float* __restrict__ out) {
    __shared__ float partial[Hh];
    int g = blockIdx.x, t = threadIdx.x;
    float v = pool[g * HC + t] * wlin[t];
    v = wave_red64(v);
    if ((t & 63) == 0) partial[t >> 6] = v;
    __syncthreads();
    if (t == 0) {
        float s = 0.f;
        #pragma unroll
        for (int h = 0; h < Hh; h++) s += partial[h];
        int c = cntg[g];
        float denom = (float)(c > 1 ? c : 1);
        out[g] = 1.f / (1.f + __expf(-s / denom));
    }
}

extern "C" void kernel_launch(void* const* d_in, const int* in_sizes, int n_in,
                              void* d_out, int out_size, void* d_ws, size_t ws_size,
                              hipStream_t stream) {
    const float* x        = (const float*)d_in[0];
    const float* ea       = (const float*)d_in[1];
    const int*   eidx     = (const int*)d_in[2];
    const int*   batch    = (const int*)d_in[3];
    const float* w1       = (const float*)d_in[4];
    const float* att_src1 = (const float*)d_in[5];
    const float* att_dst1 = (const float*)d_in[6];
    const float* we1      = (const float*)d_in[7];
    const float* atte1    = (const float*)d_in[8];
    const float* b1       = (const float*)d_in[9];
    const float* w2       = (const float*)d_in[10];
    const float* att_src2 = (const float*)d_in[11];
    const float* att_dst2 = (const float*)d_in[12];
    const float* we2      = (const float*)d_in[13];
    const float* atte2    = (const float*)d_in[14];
    const float* b2       = (const float*)d_in[15];
    const float* wlin     = (const float*)d_in[16];
    float* out = (float*)d_out;

    char* ws = (char*)d_ws;
    unsigned* h1bf = (unsigned*)(ws + OFF_H1BF);     // also h2bf
    unsigned* x2bf = (unsigned*)(ws + OFF_X2BF);
    float* att  = (float*)(ws + OFF_ATT);
    float* den  = (float*)(ws + OFF_DEN);
    float* as1  = (float*)(ws + OFF_AS1);
    float* ad1  = (float*)(ws + OFF_AD1);
    float* as2  = (float*)(ws + OFF_AS2);
    float* ad2  = (float*)(ws + OFF_AD2);
    int*   offs = (int*)(ws + OFF_OFFS);
    int*   esrc = (int*)(ws + OFF_ESRC);
    float* eea  = (float*)(ws + OFF_EEA);
    unsigned short* w2bf = (unsigned short*)(ws + OFF_W2BF);
    int*   cnt  = (int*)(ws + OFF_CNT);
    int*   cnt2 = (int*)(ws + OFF_CNT2);
    int*   cntg = (int*)(ws + OFF_CNTG);
    float* pool = (float*)(ws + OFF_POOL);
    float* scal = (float*)(ws + OFF_SCAL);

    const int* src = eidx;
    const int* dst = eidx + Ee;

    hipMemsetAsync(ws + OFF_ZERO, 0, ZERO_BYTES, stream);

    k_prep<<<256, 256, 0, stream>>>(ea, scal, w2, w2bf);
    k_wedot<<<1, HC, 0, stream>>>(we1, atte1, we2, atte2, scal);

    k_h1<<<Nn, HW, 0, stream>>>(x, w1, att_src1, att_dst1, h1bf, as1, ad1);

    int ecb = (EP + 255) / 256;
    k_count<<<ecb, 256, 0, stream>>>(dst, cnt, batch, cntg);
    k_scan<<<1, 1024, 0, stream>>>(cnt, offs);
    k_scatter<<<ecb, 256, 0, stream>>>(src, dst, ea, offs, cnt2, esrc, eea, scal);

    int nhb = (Nn * Hh + 255) / 256;
    k_att<1><<<nhb, 256, 0, stream>>>(as1, ad1, offs, esrc, eea, scal, att, den);
    k_agg<1><<<Nn / 2, 192, 0, stream>>>((const uint2*)h1bf, att, den, offs, esrc, b1, nullptr,
                                         (uint2*)x2bf, nullptr);

    k_gemm<<<(Nn + 31) / 32, 256, 0, stream>>>((const unsigned short*)x2bf, w2bf, (unsigned short*)h1bf);
    k_attn2<<<Nn, HW, 0, stream>>>(h1bf, att_src2, att_dst2, as2, ad2);

    k_att<2><<<nhb, 256, 0, stream>>>(as2, ad2, offs, esrc, eea, scal, att, den);
    k_agg<2><<<Nn / 2, 192, 0, stream>>>((const uint2*)h1bf, att, den, offs, esrc, b2, batch,
                                         nullptr, pool);

    k_final<<<Gg, HC, 0, stream>>>(pool, cntg, wlin, out);
}

// Round 13
// 507.132 us; speedup vs baseline: 1.1427x; 1.1427x over previous
//
#include <hip/hip_runtime.h>
#include <hip/hip_bf16.h>

// Problem constants
constexpr int Nn  = 20000;
constexpr int Ee  = 320000;
constexpr int Hh  = 6;
constexpr int HC  = 384;   // Hh*64
constexpr int Gg  = 64;
constexpr int NF  = 6;
constexpr int EP  = Ee + Nn;  // edges incl self-loops
constexpr int HW  = HC / 2;   // 192 packed u32 words per node row

typedef __attribute__((ext_vector_type(8))) short short8;
typedef __attribute__((ext_vector_type(4))) float f32x4;

// ---------------- workspace layout (bytes) ----------------
constexpr size_t ALN(size_t x) { return (x + 255) & ~(size_t)255; }
constexpr size_t OFF_H1BF = 0;                                   // N*192 u32 (h1, reused as h2)
constexpr size_t OFF_X2BF = ALN(OFF_H1BF + (size_t)Nn*HW*4);     // N*192 u32
constexpr size_t OFF_ATT  = ALN(OFF_X2BF + (size_t)Nn*HW*4);     // EP*6 f32 (alpha scratch -> e values)
constexpr size_t OFF_DEN  = ALN(OFF_ATT  + (size_t)EP*Hh*4);     // N*6 f32 (softmax denominators)
constexpr size_t OFF_AS1  = ALN(OFF_DEN  + (size_t)Nn*Hh*4);
constexpr size_t OFF_AD1  = ALN(OFF_AS1  + (size_t)Nn*Hh*4);
constexpr size_t OFF_AS2  = ALN(OFF_AD1  + (size_t)Nn*Hh*4);
constexpr size_t OFF_AD2  = ALN(OFF_AS2  + (size_t)Nn*Hh*4);
constexpr size_t OFF_OFFS = ALN(OFF_AD2  + (size_t)Nn*Hh*4);     // (N+1) int
constexpr size_t OFF_ESRC = ALN(OFF_OFFS + (size_t)(Nn+1)*4);
constexpr size_t OFF_EEA  = ALN(OFF_ESRC + (size_t)EP*4);
constexpr size_t OFF_W2BF = ALN(OFF_EEA  + (size_t)EP*4);        // 384*384 bf16
// ---- zeroed block (single memset) ----
constexpr size_t OFF_ZERO = ALN(OFF_W2BF + (size_t)HC*HC*2);
constexpr size_t OFF_CNT  = OFF_ZERO;                            // N int
constexpr size_t OFF_CNT2 = OFF_CNT  + (size_t)Nn*4;             // N int
constexpr size_t OFF_CNTG = OFF_CNT2 + (size_t)Nn*4;             // G int
constexpr size_t OFF_POOL = OFF_CNTG + (size_t)Gg*4;             // G*HC f32
constexpr size_t OFF_SCAL = OFF_POOL + (size_t)Gg*HC*4;          // 64 f32
constexpr size_t ZERO_BYTES = OFF_SCAL + 64*4 - OFF_ZERO;

// ---------------- helpers ----------------
__device__ __forceinline__ float wave_red64(float v) {
    #pragma unroll
    for (int o = 32; o; o >>= 1) v += __shfl_down(v, o);
    return v;
}
__device__ __forceinline__ unsigned short f2bf(float f) {
    union { float f; unsigned u; } v; v.f = f;
    return (unsigned short)((v.u + 0x7fffu + ((v.u >> 16) & 1u)) >> 16);
}
__device__ __forceinline__ unsigned pack2(float a, float b) {
    return (unsigned)f2bf(a) | ((unsigned)f2bf(b) << 16);
}
__device__ __forceinline__ float blo(unsigned w) { union { unsigned u; float f; } v; v.u = w << 16; return v.f; }
__device__ __forceinline__ float bhi(unsigned w) { union { unsigned u; float f; } v; v.u = w & 0xffff0000u; return v.f; }

// -------- fused: mean of edge_attr + w2->bf16 --------
__global__ void k_prep(const float* __restrict__ ea, float* __restrict__ scal,
                       const float* __restrict__ w2, unsigned short* __restrict__ w2bf) {
    int i = blockIdx.x * blockDim.x + threadIdx.x;
    int stride = gridDim.x * blockDim.x;
    float v = 0.f;
    for (int j = i; j < Ee; j += stride) v += ea[j];
    v = wave_red64(v);
    if ((threadIdx.x & 63) == 0) atomicAdd(&scal[0], v);
    for (int j = i; j < HC * HC; j += stride) w2bf[j] = f2bf(w2[j]);
}

// -------- we_dot[h] for both layers --------
__global__ void k_wedot(const float* __restrict__ we1, const float* __restrict__ atte1,
                        const float* __restrict__ we2, const float* __restrict__ atte2,
                        float* __restrict__ scal) {
    int t = threadIdx.x;  // 384
    float p1 = we1[t] * atte1[t];
    float p2 = we2[t] * atte2[t];
    p1 = wave_red64(p1);
    p2 = wave_red64(p2);
    if ((t & 63) == 0) { int h = t >> 6; scal[1 + h] = p1; scal[7 + h] = p2; }
}

// -------- h1 = x @ W1^T (bf16 packed), attention dots --------
__global__ __launch_bounds__(HW) void k_h1(const float* __restrict__ x, const float* __restrict__ w1,
                                           const float* __restrict__ asrc, const float* __restrict__ adst,
                                           unsigned* __restrict__ h1bf, float* __restrict__ as_, float* __restrict__ ad_) {
    int n = blockIdx.x, t = threadIdx.x;
    int c0 = 2 * t, c1 = c0 + 1;
    float xv[NF];
    #pragma unroll
    for (int k = 0; k < NF; k++) xv[k] = x[n * NF + k];
    float a0 = 0.f, a1 = 0.f;
    #pragma unroll
    for (int k = 0; k < NF; k++) { a0 += xv[k] * w1[c0 * NF + k]; a1 += xv[k] * w1[c1 * NF + k]; }
    h1bf[(size_t)n * HW + t] = pack2(a0, a1);
    float s = a0 * asrc[c0] + a1 * asrc[c1];
    float d = a0 * adst[c0] + a1 * adst[c1];
    #pragma unroll
    for (int o = 16; o; o >>= 1) { s += __shfl_xor(s, o); d += __shfl_xor(d, o); }
    if ((t & 31) == 0) { int h = t >> 5; as_[n * Hh + h] = s; ad_[n * Hh + h] = d; }
}

// -------- CSR build: count incoming edges + per-graph node counts --------
__global__ void k_count(const int* __restrict__ dst, int* __restrict__ cnt,
                        const int* __restrict__ batch, int* __restrict__ cntg) {
    int i = blockIdx.x * blockDim.x + threadIdx.x;
    if (i < EP) {
        int d = (i < Ee) ? dst[i] : (i - Ee);
        atomicAdd(&cnt[d], 1);
    }
    if (i < Nn) atomicAdd(&cntg[batch[i]], 1);
}

__global__ __launch_bounds__(1024) void k_scan(const int* __restrict__ cnt, int* __restrict__ offs) {
    __shared__ int wsum[16];
    __shared__ int carry_s;
    int t = threadIdx.x, lane = t & 63, wid = t >> 6;
    if (t == 0) carry_s = 0;
    __syncthreads();
    for (int base = 0; base < Nn; base += 1024) {
        int idx = base + t;
        int v = (idx < Nn) ? cnt[idx] : 0;
        int x = v;
        #pragma unroll
        for (int o = 1; o < 64; o <<= 1) { int y = __shfl_up(x, o); if (lane >= o) x += y; }
        if (lane == 63) wsum[wid] = x;
        __syncthreads();
        int wbase = 0;
        for (int i = 0; i < wid; i++) wbase += wsum[i];
        int excl = carry_s + wbase + x - v;
        if (idx < Nn) offs[idx] = excl;
        __syncthreads();
        if (t == 1023) carry_s = excl + v;
        __syncthreads();
    }
    if (t == 0) offs[Nn] = carry_s;
}

__global__ void k_scatter(const int* __restrict__ src, const int* __restrict__ dst,
                          const float* __restrict__ ea, const int* __restrict__ offs,
                          int* __restrict__ cnt2, int* __restrict__ esrc, float* __restrict__ eea,
                          const float* __restrict__ scal) {
    int i = blockIdx.x * blockDim.x + threadIdx.x;
    if (i >= EP) return;
    int d, s; float a;
    if (i < Ee) { d = dst[i]; s = src[i]; a = ea[i]; }
    else        { d = i - Ee; s = d; a = scal[0] * (1.0f / Ee); }
    int p = offs[d] + atomicAdd(&cnt2[d], 1);
    esrc[p] = s;
    eea[p]  = a;
}

// -------- per-(node,head) softmax: att[] gets e=exp(al-m); den[] gets sum --------
template <int LAYER>
__global__ void k_att(const float* __restrict__ as_, const float* __restrict__ ad_,
                      const int* __restrict__ offs, const int* __restrict__ esrc,
                      const float* __restrict__ eea, const float* __restrict__ scal,
                      float* __restrict__ att, float* __restrict__ den_out) {
    int idx = blockIdx.x * blockDim.x + threadIdx.x;
    if (idx >= Nn * Hh) return;
    int n = idx / Hh, h = idx - n * Hh;
    int s0 = offs[n], s1 = offs[n + 1];
    float adn = ad_[idx];
    float wdh = scal[(LAYER == 1 ? 1 : 7) + h];
    float m = -3.4e38f;
    // pass 1: gather (4-deep MLP), compute alpha, store raw, track max
    int j = s0;
    for (; j + 3 < s1; j += 4) {
        int sa = esrc[j], sb = esrc[j+1], sc = esrc[j+2], sd = esrc[j+3];
        float ea0 = eea[j], ea1 = eea[j+1], ea2 = eea[j+2], ea3 = eea[j+3];
        float va = as_[sa * Hh + h];
        float vb = as_[sb * Hh + h];
        float vc = as_[sc * Hh + h];
        float vd = as_[sd * Hh + h];
        float A = va + adn + ea0 * wdh; A = (A > 0.f) ? A : 0.2f * A;
        float B = vb + adn + ea1 * wdh; B = (B > 0.f) ? B : 0.2f * B;
        float C = vc + adn + ea2 * wdh; C = (C > 0.f) ? C : 0.2f * C;
        float D = vd + adn + ea3 * wdh; D = (D > 0.f) ? D : 0.2f * D;
        att[j * Hh + h] = A; att[(j+1) * Hh + h] = B;
        att[(j+2) * Hh + h] = C; att[(j+3) * Hh + h] = D;
        m = fmaxf(m, fmaxf(fmaxf(A, B), fmaxf(C, D)));
    }
    for (; j < s1; ++j) {
        int s = esrc[j];
        float al = as_[s * Hh + h] + adn + eea[j] * wdh;
        al = (al > 0.f) ? al : 0.2f * al;
        att[j * Hh + h] = al;
        m = fmaxf(m, al);
    }
    // pass 2: e = exp(al - m) over our own sequential buffer; accumulate den
    float den = 0.f;
    for (j = s0; j < s1; ++j) {
        float e = __expf(att[j * Hh + h] - m);
        att[j * Hh + h] = e;
        den += e;
    }
    den_out[idx] = den;
}

// -------- aggregation: gather-weighted sum, 1 node/block (uniform waves), 4-edge MLP --------
// 192 threads; thread owns channels 2t, 2t+1 (one u32 per row). All waves share one edge list.
template <int LAYER>
__global__ __launch_bounds__(HW) void k_agg(const unsigned* __restrict__ hbf, const float* __restrict__ att,
                                            const float* __restrict__ den, const int* __restrict__ offs,
                                            const int* __restrict__ esrc, const float* __restrict__ bias,
                                            const int* __restrict__ batch,
                                            unsigned* __restrict__ xout, float* __restrict__ pool) {
    int n = blockIdx.x, t = threadIdx.x, h = t >> 5;   // 32 threads (64 ch) per head
    int s0 = offs[n], s1 = offs[n + 1];
    float a0x = 0.f, a0y = 0.f, a1x = 0.f, a1y = 0.f;
    float a2x = 0.f, a2y = 0.f, a3x = 0.f, a3y = 0.f;
    int j = s0;
    for (; j + 3 < s1; j += 4) {
        int sa = esrc[j], sb = esrc[j+1], sc = esrc[j+2], sd = esrc[j+3];
        unsigned wa = hbf[(size_t)sa * HW + t];
        unsigned wb = hbf[(size_t)sb * HW + t];
        unsigned wc = hbf[(size_t)sc * HW + t];
        unsigned wd = hbf[(size_t)sd * HW + t];
        float fa = att[j * Hh + h],     fb = att[(j+1) * Hh + h];
        float fc = att[(j+2) * Hh + h], fd = att[(j+3) * Hh + h];
        a0x += fa * blo(wa); a0y += fa * bhi(wa);
        a1x += fb * blo(wb); a1y += fb * bhi(wb);
        a2x += fc * blo(wc); a2y += fc * bhi(wc);
        a3x += fd * blo(wd); a3y += fd * bhi(wd);
    }
    for (; j < s1; ++j) {
        int s = esrc[j];
        unsigned w = hbf[(size_t)s * HW + t];
        float f = att[j * Hh + h];
        a0x += f * blo(w); a0y += f * bhi(w);
    }
    float rden = 1.f / den[n * Hh + h];
    float o0 = (a0x + a1x + a2x + a3x) * rden + bias[2 * t];
    float o1 = (a0y + a1y + a2y + a3y) * rden + bias[2 * t + 1];
    o0 = (o0 > 0.f) ? o0 : (__expf(o0) - 1.f);
    o1 = (o1 > 0.f) ? o1 : (__expf(o1) - 1.f);
    if (LAYER == 1) {
        xout[(size_t)n * HW + t] = pack2(o0, o1);
    } else {
        float* pp = pool + batch[n] * HC + 2 * t;
        atomicAdd(pp,     o0);
        atomicAdd(pp + 1, o1);
    }
}

// -------- MFMA GEMM: h2 = x2 @ w2^T, bf16 in, bf16 out --------
__global__ __launch_bounds__(256) void k_gemm(const unsigned short* __restrict__ x2bf,
                                              const unsigned short* __restrict__ w2bf,
                                              unsigned short* __restrict__ h2bf) {
    int t = threadIdx.x, l = t & 63, w = t >> 6;
    int m0 = blockIdx.x * 32;
    int n0 = w * 96;
    int lr = l & 15, lk = l >> 4;
    f32x4 acc[2][6];
    #pragma unroll
    for (int mi = 0; mi < 2; mi++)
        #pragma unroll
        for (int f = 0; f < 6; f++) acc[mi][f] = (f32x4){0.f, 0.f, 0.f, 0.f};
    int mrow0 = m0 + lr, mrow1 = m0 + 16 + lr;
    int r0 = mrow0 < Nn ? mrow0 : Nn - 1;
    int r1 = mrow1 < Nn ? mrow1 : Nn - 1;
    for (int ks = 0; ks < HC / 32; ks++) {
        int koff = ks * 32 + lk * 8;
        short8 a0 = *(const short8*)(x2bf + (size_t)r0 * HC + koff);
        short8 a1 = *(const short8*)(x2bf + (size_t)r1 * HC + koff);
        #pragma unroll
        for (int f = 0; f < 6; f++) {
            short8 b = *(const short8*)(w2bf + (size_t)(n0 + f * 16 + lr) * HC + koff);
            acc[0][f] = __builtin_amdgcn_mfma_f32_16x16x32_bf16(a0, b, acc[0][f], 0, 0, 0);
            acc[1][f] = __builtin_amdgcn_mfma_f32_16x16x32_bf16(a1, b, acc[1][f], 0, 0, 0);
        }
    }
    #pragma unroll
    for (int mi = 0; mi < 2; mi++) {
        int rowb = m0 + mi * 16 + lk * 4;
        #pragma unroll
        for (int r = 0; r < 4; r++) {
            int row = rowb + r;
            if (row < Nn) {
                unsigned short* dp = h2bf + (size_t)row * HC + n0 + lr;
                #pragma unroll
                for (int f = 0; f < 6; f++) dp[f * 16] = f2bf(acc[mi][f][r]);
            }
        }
    }
}

// -------- attention dots for layer 2 (bf16 h2) --------
__global__ __launch_bounds__(HW) void k_attn2(const unsigned* __restrict__ h2bf, const float* __restrict__ asrc,
                                              const float* __restrict__ adst,
                                              float* __restrict__ as_, float* __restrict__ ad_) {
    int n = blockIdx.x, t = threadIdx.x;
    unsigned w = h2bf[(size_t)n * HW + t];
    float v0 = blo(w), v1 = bhi(w);
    float s = v0 * asrc[2 * t] + v1 * asrc[2 * t + 1];
    float d = v0 * adst[2 * t] + v1 * adst[2 * t + 1];
    #pragma unroll
    for (int o = 16; o; o >>= 1) { s += __shfl_xor(s, o); d += __shfl_xor(d, o); }
    if ((t & 31) == 0) { int h = t >> 5; as_[n * Hh + h] = s; ad_[n * Hh + h] = d; }
}

// -------- final: mean pool -> linear -> sigmoid --------
__global__ __launch_bounds__(HC) void k_final(const float* __restrict__ pool, const int* __restrict__ cntg,
                                              const float* __restrict__ wlin, float* __restrict__ out) {
    __shared__ float partial[Hh];
    int g = blockIdx.x, t = threadIdx.x;
    float v = pool[g * HC + t] * wlin[t];
    v = wave_red64(v);
    if ((t & 63) == 0) partial[t >> 6] = v;
    __syncthreads();
    if (t == 0) {
        float s = 0.f;
        #pragma unroll
        for (int h = 0; h < Hh; h++) s += partial[h];
        int c = cntg[g];
        float denom = (float)(c > 1 ? c : 1);
        out[g] = 1.f / (1.f + __expf(-s / denom));
    }
}

extern "C" void kernel_launch(void* const* d_in, const int* in_sizes, int n_in,
                              void* d_out, int out_size, void* d_ws, size_t ws_size,
                              hipStream_t stream) {
    const float* x        = (const float*)d_in[0];
    const float* ea       = (const float*)d_in[1];
    const int*   eidx     = (const int*)d_in[2];
    const int*   batch    = (const int*)d_in[3];
    const float* w1       = (const float*)d_in[4];
    const float* att_src1 = (const float*)d_in[5];
    const float* att_dst1 = (const float*)d_in[6];
    const float* we1      = (const float*)d_in[7];
    const float* atte1    = (const float*)d_in[8];
    const float* b1       = (const float*)d_in[9];
    const float* w2       = (const float*)d_in[10];
    const float* att_src2 = (const float*)d_in[11];
    const float* att_dst2 = (const float*)d_in[12];
    const float* we2      = (const float*)d_in[13];
    const float* atte2    = (const float*)d_in[14];
    const float* b2       = (const float*)d_in[15];
    const float* wlin     = (const float*)d_in[16];
    float* out = (float*)d_out;

    char* ws = (char*)d_ws;
    unsigned* h1bf = (unsigned*)(ws + OFF_H1BF);     // also h2bf
    unsigned* x2bf = (unsigned*)(ws + OFF_X2BF);
    float* att  = (float*)(ws + OFF_ATT);
    float* den  = (float*)(ws + OFF_DEN);
    float* as1  = (float*)(ws + OFF_AS1);
    float* ad1  = (float*)(ws + OFF_AD1);
    float* as2  = (float*)(ws + OFF_AS2);
    float* ad2  = (float*)(ws + OFF_AD2);
    int*   offs = (int*)(ws + OFF_OFFS);
    int*   esrc = (int*)(ws + OFF_ESRC);
    float* eea  = (float*)(ws + OFF_EEA);
    unsigned short* w2bf = (unsigned short*)(ws + OFF_W2BF);
    int*   cnt  = (int*)(ws + OFF_CNT);
    int*   cnt2 = (int*)(ws + OFF_CNT2);
    int*   cntg = (int*)(ws + OFF_CNTG);
    float* pool = (float*)(ws + OFF_POOL);
    float* scal = (float*)(ws + OFF_SCAL);

    const int* src = eidx;
    const int* dst = eidx + Ee;

    hipMemsetAsync(ws + OFF_ZERO, 0, ZERO_BYTES, stream);

    k_prep<<<256, 256, 0, stream>>>(ea, scal, w2, w2bf);
    k_wedot<<<1, HC, 0, stream>>>(we1, atte1, we2, atte2, scal);

    k_h1<<<Nn, HW, 0, stream>>>(x, w1, att_src1, att_dst1, h1bf, as1, ad1);

    int ecb = (EP + 255) / 256;
    k_count<<<ecb, 256, 0, stream>>>(dst, cnt, batch, cntg);
    k_scan<<<1, 1024, 0, stream>>>(cnt, offs);
    k_scatter<<<ecb, 256, 0, stream>>>(src, dst, ea, offs, cnt2, esrc, eea, scal);

    int nhb = (Nn * Hh + 255) / 256;
    k_att<1><<<nhb, 256, 0, stream>>>(as1, ad1, offs, esrc, eea, scal, att, den);
    k_agg<1><<<Nn, HW, 0, stream>>>(h1bf, att, den, offs, esrc, b1, nullptr, x2bf, nullptr);

    k_gemm<<<(Nn + 31) / 32, 256, 0, stream>>>((const unsigned short*)x2bf, w2bf, (unsigned short*)h1bf);
    k_attn2<<<Nn, HW, 0, stream>>>(h1bf, att_src2, att_dst2, as2, ad2);

    k_att<2><<<nhb, 256, 0, stream>>>(as2, ad2, offs, esrc, eea, scal, att, den);
    k_agg<2><<<Nn, HW, 0, stream>>>(h1bf, att, den, offs, esrc, b2, batch, nullptr, pool);

    k_final<<<Gg, HC, 0, stream>>>(pool, cntg, wlin, out);
}